// Round 1
// baseline (168.134 us; speedup 1.0000x reference)
//
#include <hip/hip_runtime.h>

#define DIM 160
#define SLICE (DIM * DIM)
#define TH 16
#define TW 16
#define CD 20   // output slices per block chunk; 160/CD = 8 chunks per batch

// Fused LNCC, separable order h -> w -> d, each input slice loaded ONCE.
// Per input slice z (CD+8 per chunk):
//   stage1: 144 threads load 24x24 halo of x,y (clamped), write 5 product
//           planes to S (b128).
//   stage2: 120 threads 9-tap h-sum S->T (b128 register slide); global
//           prefetch of slice z+1 issued just before, consumed next iter.
//   stage3: 64 threads 9-tap w-sum T->U (b128 slide).
//   stage4: all 256 threads (one output (h,w) column each) update 5 running
//           d-sums from U, keeping a 9-deep per-channel history in REGISTERS
//           (compile-time ring phase via 9-unrolled z loop) -> no global
//           re-read for the subtraction, no LDS ring.
// LDS planes padded +8 words so channel stride != 0 mod 32 banks.
// CD=20 (was 40): 1600 blocks = 6.25/CU so the LDS limit (5 blocks/CU
// co-resident) is reached; occupancy was grid-limited at 800 blocks.
#define SIDX(c,i,j) ((c)*680 + (i)*28 + (j))   // S: 24x28 plane (+8 pad)
#define TIDX(c,i,j) ((c)*456 + (i)*28 + (j))   // T: 16x28 plane (+8 pad)
#define UIDX(c,i,j) ((c)*260 + (i)*16 + (j))   // U: 16x16 plane (+4 pad)

__global__ __launch_bounds__(256, 4)
void lncc_kernel(const float* __restrict__ x, const float* __restrict__ y,
                 float* __restrict__ out)
{
    __shared__ __align__(16) float S[5 * 680];
    __shared__ __align__(16) float T[5 * 456];
    __shared__ __align__(16) float U[5 * 260];
    __shared__ float wsum[4];

    const int t  = threadIdx.x;
    const int w0 = blockIdx.x * TW;
    const int h0 = blockIdx.y * TH;
    const int bz = blockIdx.z;
    const int b   = bz >> 3;              // batch
    const int zo0 = (bz & 7) * CD;        // first output slice of chunk

    const float* xb = x + (size_t)b * (DIM * SLICE);
    const float* yb = y + (size_t)b * (DIM * SLICE);

    // ---- stage1 role: halo column group (h1, w41) ----
    const int h1  = t / 6;                // 0..23 valid for t<144
    const int w41 = t - h1 * 6;           // 0..5
    const int gh  = min(max(h0 - 4 + h1, 0), DIM - 1);
    const int gwb = w0 - 4 + 4 * w41;
    const bool fast = (gwb >= 0) && (gwb + 3 < DIM);
    const int jc0 = min(max(gwb + 0, 0), DIM - 1);
    const int jc1 = min(max(gwb + 1, 0), DIM - 1);
    const int jc2 = min(max(gwb + 2, 0), DIM - 1);
    const int jc3 = min(max(gwb + 3, 0), DIM - 1);

    auto load4 = [&](const float* sl) -> float4 {
        const float* row = sl + (size_t)gh * DIM;
        if (fast) return *reinterpret_cast<const float4*>(row + gwb);
        float4 r;
        r.x = row[jc0]; r.y = row[jc1]; r.z = row[jc2]; r.w = row[jc3];
        return r;
    };

    // ---- stage2 role: (channel c2, w-group w42, row-quad i02) ----
    const int c2  = t / 24;               // 0..4 for t<120
    const int r2  = t - c2 * 24;
    const int w42 = r2 >> 2;              // 0..5
    const int i02 = (r2 & 3) * 4;         // 0,4,8,12

    // ---- stage3 role: (row i3, w-group j3) ----
    const int i3 = t >> 2;                // 0..15 for t<64
    const int j3 = (t & 3) * 4;           // 0,4,8,12

    // ---- stage4 role: one output column each ----
    const int i4 = t >> 4;
    const int j4 = t & 15;

    float hist[9][5];                     // register ring (constant indices)
    float rs[5] = {0.f, 0.f, 0.f, 0.f, 0.f};
    float acc = 0.f;

    // prefetch first slice
    float4 xv = {0,0,0,0}, yv = {0,0,0,0};
    {
        const int z0 = min(max(zo0 - 4, 0), DIM - 1);
        if (t < 144) {
            xv = load4(xb + (size_t)z0 * SLICE);
            yv = load4(yb + (size_t)z0 * SLICE);
        }
    }

    const int zlast = zo0 + CD + 3;       // CD+8 input slices: zo0-4 .. zlast
    for (int base = zo0 - 4; base <= zlast; base += 9) {
        #pragma unroll
        for (int p = 0; p < 9; ++p) {
            const int zi = base + p;      // phase (zi - (zo0-4)) % 9 == p
            if (zi <= zlast) {
                // stage1: products of prefetched slice -> S
                if (t < 144) {
                    const int jw = 4 * w41;
                    *reinterpret_cast<float4*>(&S[SIDX(0, h1, jw)]) = xv;
                    *reinterpret_cast<float4*>(&S[SIDX(1, h1, jw)]) = yv;
                    *reinterpret_cast<float4*>(&S[SIDX(2, h1, jw)]) = xv * xv;
                    *reinterpret_cast<float4*>(&S[SIDX(3, h1, jw)]) = yv * yv;
                    *reinterpret_cast<float4*>(&S[SIDX(4, h1, jw)]) = xv * yv;
                }
                __syncthreads();

                // prefetch next slice (consumed next iteration, after 2 bars)
                if (t < 144 && zi < zlast) {
                    const int zn = min(max(zi + 1, 0), DIM - 1);
                    xv = load4(xb + (size_t)zn * SLICE);
                    yv = load4(yb + (size_t)zn * SLICE);
                }

                // stage2: 9-tap h-sum S->T (b128 slide over 4 rows)
                if (t < 120) {
                    const int jw = 4 * w42;
                    float4 s = {0,0,0,0};
                    #pragma unroll
                    for (int k = 0; k < 9; ++k)
                        s += *reinterpret_cast<const float4*>(&S[SIDX(c2, i02 + k, jw)]);
                    *reinterpret_cast<float4*>(&T[TIDX(c2, i02, jw)]) = s;
                    #pragma unroll
                    for (int m = 1; m < 4; ++m) {
                        s += *reinterpret_cast<const float4*>(&S[SIDX(c2, i02 + 8 + m, jw)])
                           - *reinterpret_cast<const float4*>(&S[SIDX(c2, i02 + m - 1, jw)]);
                        *reinterpret_cast<float4*>(&T[TIDX(c2, i02 + m, jw)]) = s;
                    }
                }
                __syncthreads();

                // stage3: 9-tap w-sum T->U (b128 slide, 1 wave)
                if (t < 64) {
                    #pragma unroll
                    for (int c = 0; c < 5; ++c) {
                        const float4 t0 = *reinterpret_cast<const float4*>(&T[TIDX(c, i3, j3)]);
                        const float4 t1 = *reinterpret_cast<const float4*>(&T[TIDX(c, i3, j3 + 4)]);
                        const float4 t2 = *reinterpret_cast<const float4*>(&T[TIDX(c, i3, j3 + 8)]);
                        float4 uo;
                        float s = t0.x + t0.y + t0.z + t0.w
                                + t1.x + t1.y + t1.z + t1.w + t2.x;
                        uo.x = s;
                        s += t2.y - t0.x; uo.y = s;
                        s += t2.z - t0.y; uo.z = s;
                        s += t2.w - t0.z; uo.w = s;
                        *reinterpret_cast<float4*>(&U[UIDX(c, i3, j3)]) = uo;
                    }
                }
                __syncthreads();

                // stage4: register d-ring update + ncc emit
                float u[5];
                #pragma unroll
                for (int c = 0; c < 5; ++c) {
                    u[c] = U[UIDX(c, i4, j4)];
                    rs[c] += u[c];
                    hist[p][c] = u[c];
                }
                if (zi >= zo0 + 4) {
                    const float inv = 1.0f / 729.0f;
                    const float xm = rs[0] * inv, ym = rs[1] * inv;
                    const float x2 = rs[2] * inv, y2 = rs[3] * inv;
                    const float xy = rs[4] * inv;
                    const float cross = xy - xm * ym;
                    const float vx = x2 - xm * xm;
                    const float vy = y2 - ym * ym;
                    acc += cross * cross / (vx * vy + 1e-5f);
                    const int po = (p + 1) % 9;    // slice zi-8 leaves window
                    #pragma unroll
                    for (int c = 0; c < 5; ++c)
                        rs[c] -= hist[po][c];
                }
                // stage4 U-reads are ordered before next slice's U-writes by
                // the next iteration's bar1+bar2
            }
        }
    }

    // ---- block reduction: wave shuffle, then 4 partials via LDS ----
    #pragma unroll
    for (int off = 32; off > 0; off >>= 1)
        acc += __shfl_down(acc, off, 64);
    const int wave = t >> 6;
    if ((t & 63) == 0) wsum[wave] = acc;
    __syncthreads();
    if (t == 0) {
        const float s = wsum[0] + wsum[1] + wsum[2] + wsum[3];
        atomicAdd(out, -s * (1.0f / 8192000.0f));
    }
}

extern "C" void kernel_launch(void* const* d_in, const int* in_sizes, int n_in,
                              void* d_out, int out_size, void* d_ws, size_t ws_size,
                              hipStream_t stream)
{
    const float* x = (const float*)d_in[0];
    const float* y = (const float*)d_in[1];
    float* out = (float*)d_out;

    // d_out is poisoned 0xAA before every call; accumulate atomically on zero
    hipMemsetAsync(out, 0, sizeof(float), stream);

    dim3 grid(DIM / TW, DIM / TH, 2 * (DIM / CD));  // 10 x 10 x 16 = 1600 blocks
    lncc_kernel<<<grid, 256, 0, stream>>>(x, y, out);
}